// Round 1
// baseline (266.604 us; speedup 1.0000x reference)
//
#include <hip/hip_runtime.h>

// All-pole time-varying IIR, parallelized via chunked affine-state decomposition.
//   y[t] = K[t]*x[t] - sum_m A[t][m] * y[t-1-m],  A/K linearly interpolated per frame (P=80).
// Split T=16000 into C=100 chunks of L=160 (2 frames). Per chunk the map
// (init state s) -> (final state) is affine: s_end = M_c s + f_c.
// Phase1: 31 independent lane-runs per chunk build M_c (unit-state responses) and f_c
//         (zero-state, real-input response).
// Phase2: per batch, sequential scan s <- M_c s + f_c over 100 chunks; stores s_start per chunk.
// Phase3: one chunk per lane re-runs the exact recurrence from s_start and writes y.

#define Bb 64
#define Tt 16000
#define Nn 200
#define Pp 80
#define Mm 30
#define Dd 31
#define Cc 100
#define Ll 160  // 2 frames per chunk

// ws layout: Mf[B*C][31][30] floats (23.808 MB), then Sstart[B*C][30] floats (0.768 MB)
#define MF_FLOATS ((size_t)Bb * Cc * 31 * Mm)
#define SS_FLOATS ((size_t)Bb * Cc * Mm)

// ---------------- Phase 1: per-chunk transition matrices ----------------
__global__ __launch_bounds__(256) void phase1(const float* __restrict__ x,
                                              const float* __restrict__ a,
                                              float* __restrict__ Mf) {
  const int tid = threadIdx.x;
  const int wave = tid >> 6;
  const int lane = tid & 63;
  const int half = lane >> 5;
  const int role = lane & 31;          // 0..29 unit-state cols, 30 = input-driven, 31 idle
  const int ch = ((blockIdx.x * 4 + wave) << 1) + half;
  const int b = ch / Cc;
  const int c = ch % Cc;
  const int t0 = c * Ll;

  float h[Mm];
#pragma unroll
  for (int m = 0; m < Mm; ++m) h[m] = (role == m) ? 1.0f : 0.0f;
  const bool useg = (role == 30);

  for (int fr = 0; fr < 2; ++fr) {
    const int n = 2 * c + fr;
    const float* p0 = a + ((size_t)b * Nn + n) * Dd;
    const float* p1 = a + ((size_t)b * Nn + min(n + 1, Nn - 1)) * Dd;
    float c0[Mm], dc[Mm];
#pragma unroll
    for (int m = 0; m < Mm; ++m) {
      float v0 = p0[m + 1];
      c0[m] = v0;
      dc[m] = p1[m + 1] - v0;
    }
    const float K0 = p0[0], dK = p1[0] - K0;
    const float* xp = x + (size_t)b * Tt + t0 + fr * Pp;
    for (int i = 0; i < Pp; ++i) {
      const float f = (float)i * (1.0f / Pp);
      float acc = 0.f;
#pragma unroll
      for (int m = 0; m < Mm; ++m) {
        float am = fmaf(dc[m], f, c0[m]);
        acc = fmaf(am, h[m], acc);
      }
      float inp = 0.f;
      if (useg) {
        float Kt = fmaf(dK, f, K0);
        inp = Kt * xp[i];
      }
      const float y = inp - acc;
#pragma unroll
      for (int m = Mm - 1; m > 0; --m) h[m] = h[m - 1];
      h[0] = y;
    }
  }
  if (role <= 30) {
    float* dst = Mf + ((size_t)ch * 31 + role) * Mm;
#pragma unroll
    for (int m = 0; m < Mm; ++m) dst[m] = h[m];
  }
}

// ---------------- Phase 2: sequential scan of chunk states ----------------
__device__ __forceinline__ void p2_load(const float* __restrict__ Mf, int ch, int lane,
                                        float (&R)[Mm + 1]) {
  const float* nb = Mf + (size_t)ch * (31 * Mm);
  if (lane < Mm) {
#pragma unroll
    for (int j = 0; j <= Mm; ++j) R[j] = nb[j * Mm + lane];  // R[j]=M[lane][j], R[30]=f[lane]
  }
}

__device__ __forceinline__ float p2_step(float s, const float (&CUR)[Mm + 1]) {
  float acc = CUR[Mm];
#pragma unroll
  for (int j = 0; j < Mm; ++j) {
    float sj = __shfl(s, j, 64);
    acc = fmaf(CUR[j], sj, acc);
  }
  return acc;
}

__global__ __launch_bounds__(64) void phase2(const float* __restrict__ Mf,
                                             float* __restrict__ Sstart) {
  const int b = blockIdx.x;
  const int lane = threadIdx.x;
  const int chbase = b * Cc;
  float s = 0.f;
  float MA[Mm + 1] = {};
  float MB[Mm + 1] = {};
  p2_load(Mf, chbase, lane, MA);
  for (int c = 0; c < Cc; c += 2) {
    // prefetch next while computing current (ping-pong, static indexing)
    p2_load(Mf, chbase + c + 1, lane, MB);
    if (lane < Mm) Sstart[(size_t)(chbase + c) * Mm + lane] = s;
    s = p2_step(s, MA);
    if (c + 2 < Cc) p2_load(Mf, chbase + c + 2, lane, MA);
    if (lane < Mm) Sstart[(size_t)(chbase + c + 1) * Mm + lane] = s;
    s = p2_step(s, MB);
  }
}

// ---------------- Phase 3: exact re-run per chunk, one chunk per lane ----------------
__global__ __launch_bounds__(256) void phase3(const float* __restrict__ x,
                                              const float* __restrict__ a,
                                              const float* __restrict__ Sstart,
                                              float* __restrict__ out) {
  const int ch = blockIdx.x * 256 + threadIdx.x;
  if (ch >= Bb * Cc) return;
  const int b = ch / Cc;
  const int c = ch % Cc;
  const int t0 = c * Ll;
  float h[Mm];
  const float* sp = Sstart + (size_t)ch * Mm;
#pragma unroll
  for (int m = 0; m < Mm; ++m) h[m] = sp[m];
  for (int fr = 0; fr < 2; ++fr) {
    const int n = 2 * c + fr;
    const float* p0 = a + ((size_t)b * Nn + n) * Dd;
    const float* p1 = a + ((size_t)b * Nn + min(n + 1, Nn - 1)) * Dd;
    float c0[Mm], dc[Mm];
#pragma unroll
    for (int m = 0; m < Mm; ++m) {
      float v0 = p0[m + 1];
      c0[m] = v0;
      dc[m] = p1[m + 1] - v0;
    }
    const float K0 = p0[0], dK = p1[0] - K0;
    const float* xp = x + (size_t)b * Tt + t0 + fr * Pp;
    float* yp = out + (size_t)b * Tt + t0 + fr * Pp;
    for (int i = 0; i < Pp; ++i) {
      const float f = (float)i * (1.0f / Pp);
      float acc = 0.f;
#pragma unroll
      for (int m = 0; m < Mm; ++m) {
        float am = fmaf(dc[m], f, c0[m]);
        acc = fmaf(am, h[m], acc);
      }
      const float Kt = fmaf(dK, f, K0);
      const float y = fmaf(Kt, xp[i], -acc);
      yp[i] = y;
#pragma unroll
      for (int m = Mm - 1; m > 0; --m) h[m] = h[m - 1];
      h[0] = y;
    }
  }
}

// ---------------- Fallback (no workspace needed): serial, one lane per batch ----------------
__global__ void naive_kernel(const float* __restrict__ x, const float* __restrict__ a,
                             float* __restrict__ out) {
  const int b = blockIdx.x * blockDim.x + threadIdx.x;
  if (b >= Bb) return;
  float h[Mm];
#pragma unroll
  for (int m = 0; m < Mm; ++m) h[m] = 0.f;
  for (int n = 0; n < Nn; ++n) {
    const float* p0 = a + ((size_t)b * Nn + n) * Dd;
    const float* p1 = a + ((size_t)b * Nn + min(n + 1, Nn - 1)) * Dd;
    float c0[Mm], dc[Mm];
#pragma unroll
    for (int m = 0; m < Mm; ++m) {
      float v0 = p0[m + 1];
      c0[m] = v0;
      dc[m] = p1[m + 1] - v0;
    }
    const float K0 = p0[0], dK = p1[0] - K0;
    const float* xp = x + (size_t)b * Tt + n * Pp;
    float* yp = out + (size_t)b * Tt + n * Pp;
    for (int i = 0; i < Pp; ++i) {
      const float f = (float)i * (1.0f / Pp);
      float acc = 0.f;
#pragma unroll
      for (int m = 0; m < Mm; ++m) acc = fmaf(fmaf(dc[m], f, c0[m]), h[m], acc);
      const float y = fmaf(fmaf(dK, f, K0), xp[i], -acc);
      yp[i] = y;
#pragma unroll
      for (int m = Mm - 1; m > 0; --m) h[m] = h[m - 1];
      h[0] = y;
    }
  }
}

extern "C" void kernel_launch(void* const* d_in, const int* in_sizes, int n_in,
                              void* d_out, int out_size, void* d_ws, size_t ws_size,
                              hipStream_t stream) {
  const float* x = (const float*)d_in[0];   // (64, 16000) f32
  const float* a = (const float*)d_in[1];   // (64, 200, 31) f32
  float* out = (float*)d_out;               // (64, 16000) f32

  const size_t need = (MF_FLOATS + SS_FLOATS) * sizeof(float);
  if (ws_size < need) {
    naive_kernel<<<1, 64, 0, stream>>>(x, a, out);
    return;
  }
  float* Mf = (float*)d_ws;
  float* Sstart = Mf + MF_FLOATS;

  // Phase1: 6400 chunks, 2 chunks per wave, 4 waves per block -> 800 blocks
  phase1<<<800, 256, 0, stream>>>(x, a, Mf);
  // Phase2: one wave per batch
  phase2<<<64, 64, 0, stream>>>(Mf, Sstart);
  // Phase3: one chunk per lane -> 6400 lanes
  phase3<<<25, 256, 0, stream>>>(x, a, Sstart, out);
}